// Round 1
// baseline (280.250 us; speedup 1.0000x reference)
//
#include <hip/hip_runtime.h>
#include <stdint.h>

typedef __bf16 bf16;
typedef __bf16 bf16x8 __attribute__((ext_vector_type(8)));
typedef float f32x4 __attribute__((ext_vector_type(4)));

#define DEVI static __device__ __forceinline__

// async global->LDS, 16B per lane. LDS dest = wave-uniform base + lane*16.
DEVI void async_ld16(void* lds, const void* g) {
  __builtin_amdgcn_global_load_lds(
      (const __attribute__((address_space(1))) void*)(uintptr_t)g,
      (__attribute__((address_space(3))) void*)(uint32_t)(uintptr_t)lds,
      16, 0, 0);
}

DEVI f32x4 vsplat(float v) { f32x4 r; r.x = v; r.y = v; r.z = v; r.w = v; return r; }
DEVI f32x4 vmax4(f32x4 a, f32x4 b) {
  f32x4 r; r.x = fmaxf(a.x, b.x); r.y = fmaxf(a.y, b.y);
  r.z = fmaxf(a.z, b.z); r.w = fmaxf(a.w, b.w); return r;
}
DEVI f32x4 vexp_sub(f32x4 a, f32x4 m) {
  f32x4 r; r.x = __expf(a.x - m.x); r.y = __expf(a.y - m.y);
  r.z = __expf(a.z - m.z); r.w = __expf(a.w - m.w); return r;
}
DEVI f32x4 shfl_xor4(f32x4 v, int off) {
  f32x4 r; r.x = __shfl_xor(v.x, off); r.y = __shfl_xor(v.y, off);
  r.z = __shfl_xor(v.z, off); r.w = __shfl_xor(v.w, off); return r;
}

// ---------------- fp32 -> bf16 convert (vectorized, 8 elems/thread) -------------
__global__ __launch_bounds__(256) void cvt_bf16_kernel(
    const float* __restrict__ in, bf16* __restrict__ out, int n8) {
  int i = blockIdx.x * 256 + threadIdx.x;
  if (i >= n8) return;
  const float4* p = (const float4*)in + (size_t)i * 2;
  float4 a = p[0], b = p[1];
  bf16x8 o;
  o[0] = (bf16)a.x; o[1] = (bf16)a.y; o[2] = (bf16)a.z; o[3] = (bf16)a.w;
  o[4] = (bf16)b.x; o[5] = (bf16)b.y; o[6] = (bf16)b.z; o[7] = (bf16)b.w;
  *((bf16x8*)out + i) = o;
}

// ---------------- GEMM: C[m][n] = sum_k A[m][k]*B[n][k]  (both row-major, ld=K) ---
// 128x128 tile, BK=32, 256 thr = 4 waves (2x2), each wave 64x64 via 4x4 16x16x32 mfma.
// LDS staged with global_load_lds(16B); XOR swizzle (slot ^= (row>>1)&3) applied by
// pre-swizzling the GLOBAL source column (rule #21); reads use the same XOR.
// MODE 0: qkv epilogue -> Q(*0.125)/K as [b][h][n][64], V transposed as [b][h][d][1024], bf16
// MODE 1: proj epilogue -> fp32 out[m*N+n] + bias[n]
template <int MODE>
__global__ __launch_bounds__(256) void gemm_bt_kernel(
    const bf16* __restrict__ A, const bf16* __restrict__ B, int K, int N,
    bf16* __restrict__ q_out, bf16* __restrict__ k_out, bf16* __restrict__ vt_out,
    float* __restrict__ f_out, const float* __restrict__ bias) {
  __shared__ bf16 As[128 * 32];
  __shared__ bf16 Bs[128 * 32];
  const int t = threadIdx.x;
  const int lane = t & 63, g = lane >> 4, ql = lane & 15;
  const int w = t >> 6, wr = w >> 1, wc = w & 1;
  const int wbase = __builtin_amdgcn_readfirstlane(t & 192);
  const int m0 = blockIdx.y * 128, n0 = blockIdx.x * 128;

  f32x4 acc[4][4];
#pragma unroll
  for (int i = 0; i < 4; i++)
#pragma unroll
    for (int j = 0; j < 4; j++) acc[i][j] = vsplat(0.f);

  for (int kt = 0; kt < K; kt += 32) {
    __syncthreads();
#pragma unroll
    for (int i = 0; i < 2; i++) {
      int unit = i * 256 + t;
      int row = unit >> 2;
      int su = (unit & 3) ^ ((row >> 1) & 3);  // unswizzled 16B slot for this LDS pos
      async_ld16(As + (size_t)(i * 256 + wbase) * 8,
                 A + (size_t)(m0 + row) * K + kt + su * 8);
      async_ld16(Bs + (size_t)(i * 256 + wbase) * 8,
                 B + (size_t)(n0 + row) * K + kt + su * 8);
    }
    __syncthreads();
    bf16x8 af[4], bfr[4];
#pragma unroll
    for (int f = 0; f < 4; f++) {
      int ra = wr * 64 + f * 16 + ql;
      af[f] = *(const bf16x8*)(As + ra * 32 + ((g ^ ((ra >> 1) & 3)) * 8));
      int rb = wc * 64 + f * 16 + ql;
      bfr[f] = *(const bf16x8*)(Bs + rb * 32 + ((g ^ ((rb >> 1) & 3)) * 8));
    }
#pragma unroll
    for (int fm = 0; fm < 4; fm++)
#pragma unroll
      for (int fn = 0; fn < 4; fn++)
        acc[fm][fn] = __builtin_amdgcn_mfma_f32_16x16x32_bf16(af[fm], bfr[fn],
                                                              acc[fm][fn], 0, 0, 0);
  }

  // D layout: row(m) = g*4 + r (+16*fm), col(n) = ql (+16*fn)
  if (MODE == 0) {
#pragma unroll
    for (int fm = 0; fm < 4; fm++) {
#pragma unroll
      for (int fn = 0; fn < 4; fn++) {
        int n = n0 + wc * 64 + fn * 16 + ql;
#pragma unroll
        for (int r = 0; r < 4; r++) {
          int m = m0 + wr * 64 + fm * 16 + g * 4 + r;
          int b = m >> 10, nn = m & 1023;
          float v = acc[fm][fn][r];
          if (n < 768) {  // Q, pre-scaled by 1/sqrt(64)
            int h = n >> 6, d = n & 63;
            q_out[((size_t)((b * 12 + h) * 1024 + nn)) * 64 + d] = (bf16)(v * 0.125f);
          } else if (n < 1536) {  // K
            int c = n - 768, h = c >> 6, d = c & 63;
            k_out[((size_t)((b * 12 + h) * 1024 + nn)) * 64 + d] = (bf16)v;
          } else {  // V transposed: [b][h][d][n]
            int c = n - 1536, h = c >> 6, d = c & 63;
            vt_out[((size_t)((b * 12 + h) * 64 + d)) * 1024 + nn] = (bf16)v;
          }
        }
      }
    }
  } else {
#pragma unroll
    for (int fm = 0; fm < 4; fm++) {
#pragma unroll
      for (int fn = 0; fn < 4; fn++) {
        int n = n0 + wc * 64 + fn * 16 + ql;
        float bv = bias[n];
#pragma unroll
        for (int r = 0; r < 4; r++) {
          int m = m0 + wr * 64 + fm * 16 + g * 4 + r;
          f_out[(size_t)m * N + n] = acc[fm][fn][r] + bv;
        }
      }
    }
  }
}

// ---------------- gate mask: mask[b,k] = sigmoid(dot768(q_last, k_row)/12) --------
// (Q already pre-scaled by 1/8, heads partition the 768 dims.) One wave per (b,k).
__global__ __launch_bounds__(256) void mask_kernel(
    const bf16* __restrict__ qb, const bf16* __restrict__ kb, float* __restrict__ mout) {
  int t = threadIdx.x, lane = t & 63;
  int wid = blockIdx.x * 4 + (t >> 6);
  int b = wid >> 10, kcol = wid & 1023;
  float acc = 0.f;
#pragma unroll
  for (int h = 0; h < 12; h++) {
    const bf16* qr = qb + ((size_t)((b * 12 + h) * 1024 + 1023)) * 64;
    const bf16* kr = kb + ((size_t)((b * 12 + h) * 1024 + kcol)) * 64;
    acc += (float)qr[lane] * (float)kr[lane];
  }
#pragma unroll
  for (int off = 32; off >= 1; off >>= 1) acc += __shfl_xor(acc, off);
  if (lane == 0) {
    float x = acc * (1.f / 12.f);
    mout[(b << 10) + kcol] = 1.f / (1.f + __expf(-x));
  }
}

// ---------------- flash attention with post-softmax gate --------------------------
// grid: 96 (b,h) x 16 q-tiles; 4 waves x 16 q-rows each. KV tile = 64.
// O = (sum_k e^{s-m} mask_k v_k) / (sum_k e^{s-m})  [denominator unmasked]
__global__ __launch_bounds__(256) void attn_kernel(
    const bf16* __restrict__ qb, const bf16* __restrict__ kb,
    const bf16* __restrict__ vt, const float* __restrict__ maskp,
    bf16* __restrict__ ob, const int* __restrict__ cdp) {
  __shared__ bf16 Ks[64 * 64];       // [kk][d], 16B slots XOR-swizzled by kk&7
  __shared__ bf16 Vs[64 * 64];       // [d][kk], swizzled by d&7
  __shared__ bf16 Ps[4 * 16 * 64];   // per-wave P, swizzled by q&7
  const int t = threadIdx.x;
  const int lane = t & 63, g = lane >> 4, ql = lane & 15;
  const int w = t >> 6;
  const int wbase = __builtin_amdgcn_readfirstlane(t & 192);
  const int bid = blockIdx.x;
  const int bh = bid >> 4, qt = bid & 15;
  const int b = bh / 12, h = bh - b * 12;
  const bf16* Qp = qb + (size_t)bh * 1024 * 64;
  const bf16* Kp = kb + (size_t)bh * 1024 * 64;
  const bf16* Vp = vt + (size_t)bh * 64 * 1024;
  const int q0 = qt * 64 + w * 16;
  const bool applyMask = (cdp[0] >= 9);
  const float* mrow = maskp + b * 1024;
  bf16* Pw = Ps + w * 1024;

  // hoist Q into registers: lane holds Q[q0+ql][dh*32 + g*8 .. +8]
  bf16x8 qreg[2];
#pragma unroll
  for (int dh = 0; dh < 2; dh++)
    qreg[dh] = *(const bf16x8*)(Qp + (size_t)(q0 + ql) * 64 + dh * 32 + g * 8);

  f32x4 m4 = vsplat(-1e30f), D4 = vsplat(0.f);
  f32x4 o[4];
#pragma unroll
  for (int fd = 0; fd < 4; fd++) o[fd] = vsplat(0.f);

  for (int kv0 = 0; kv0 < 1024; kv0 += 64) {
    __syncthreads();
#pragma unroll
    for (int i = 0; i < 2; i++) {
      int unit = i * 256 + t;
      int row = unit >> 3;                   // kk for K, d for V
      int su = (unit & 7) ^ (row & 7);       // unswizzled 8-elem slot
      async_ld16(Ks + (size_t)(i * 256 + wbase) * 8,
                 Kp + (size_t)(kv0 + row) * 64 + su * 8);
      async_ld16(Vs + (size_t)(i * 256 + wbase) * 8,
                 Vp + (size_t)row * 1024 + kv0 + su * 8);
    }
    __syncthreads();

    // S = Q K^T  (rows q = g*4+r, cols kk = fk*16+ql); Q pre-scaled
    f32x4 s[4];
#pragma unroll
    for (int fk = 0; fk < 4; fk++) {
      int kkr = fk * 16 + ql;
      s[fk] = vsplat(0.f);
#pragma unroll
      for (int dh = 0; dh < 2; dh++) {
        bf16x8 kf = *(const bf16x8*)(Ks + kkr * 64 + (((dh * 4 + g) ^ (kkr & 7)) * 8));
        s[fk] = __builtin_amdgcn_mfma_f32_16x16x32_bf16(qreg[dh], kf, s[fk], 0, 0, 0);
      }
    }

    // online softmax (per q-row r; row spread over 16 lanes of same g + 4 fk regs)
    f32x4 tm = vmax4(vmax4(s[0], s[1]), vmax4(s[2], s[3]));
#pragma unroll
    for (int off = 1; off <= 8; off <<= 1) tm = vmax4(tm, shfl_xor4(tm, off));
    f32x4 mn = vmax4(m4, tm);
    f32x4 sc = vexp_sub(m4, mn);
    f32x4 p[4];
#pragma unroll
    for (int fk = 0; fk < 4; fk++) p[fk] = vexp_sub(s[fk], mn);
    f32x4 rs = p[0] + p[1] + p[2] + p[3];
#pragma unroll
    for (int off = 1; off <= 8; off <<= 1) rs = rs + shfl_xor4(rs, off);
    D4 = D4 * sc + rs;
    m4 = mn;
#pragma unroll
    for (int fd = 0; fd < 4; fd++) o[fd] *= sc;

    // gate + pack P (bf16) into per-wave LDS, swizzled
#pragma unroll
    for (int fk = 0; fk < 4; fk++) {
      int kkc = fk * 16 + ql;
      float mc = applyMask ? mrow[kv0 + kkc] : 1.0f;
      f32x4 pv = p[fk] * mc;
#pragma unroll
      for (int r = 0; r < 4; r++) {
        int q = g * 4 + r;
        Pw[q * 64 + (((kkc >> 3) ^ (q & 7)) * 8) + (kkc & 7)] = (bf16)pv[r];
      }
    }

    // O += P V  (A = P rows q, inner kk; B = V[kk][d] read from Vt rows d)
#pragma unroll
    for (int kh = 0; kh < 2; kh++) {
      bf16x8 pf = *(const bf16x8*)(Pw + ql * 64 + (((kh * 4 + g) ^ (ql & 7)) * 8));
#pragma unroll
      for (int fd = 0; fd < 4; fd++) {
        int dr = fd * 16 + ql;
        bf16x8 vf = *(const bf16x8*)(Vs + dr * 64 + (((kh * 4 + g) ^ (dr & 7)) * 8));
        o[fd] = __builtin_amdgcn_mfma_f32_16x16x32_bf16(pf, vf, o[fd], 0, 0, 0);
      }
    }
  }

  // epilogue: O / D -> [b][n][h*64+d] bf16
  f32x4 dinv;
  dinv.x = 1.f / D4.x; dinv.y = 1.f / D4.y; dinv.z = 1.f / D4.z; dinv.w = 1.f / D4.w;
#pragma unroll
  for (int fd = 0; fd < 4; fd++) {
    f32x4 val = o[fd] * dinv;
#pragma unroll
    for (int r = 0; r < 4; r++) {
      int q = q0 + g * 4 + r;
      ob[((size_t)(b * 1024 + q)) * 768 + h * 64 + fd * 16 + ql] = (bf16)val[r];
    }
  }
}

// ---------------- launch ---------------------------------------------------------
extern "C" void kernel_launch(void* const* d_in, const int* in_sizes, int n_in,
                              void* d_out, int out_size, void* d_ws, size_t ws_size,
                              hipStream_t stream) {
  const float* x     = (const float*)d_in[0];   // (8,1024,768)
  const float* qkvw  = (const float*)d_in[1];   // (2304,768)
  const float* projw = (const float*)d_in[2];   // (768,768)
  const float* projb = (const float*)d_in[3];   // (768,)
  const int*   cd    = (const int*)d_in[4];     // scalar
  float* out  = (float*)d_out;                  // (8,1024,768) fp32
  float* mout = out + 6291456;                  // mask (8,1024) fp32

  char* p = (char*)d_ws;
  bf16* xb    = (bf16*)p; p += 12582912;  // x bf16, reused as attn-out buffer
  bf16* wqkvb = (bf16*)p; p += 3538944;
  bf16* wpb   = (bf16*)p; p += 1179648;
  bf16* qb    = (bf16*)p; p += 12582912;  // [b][h][n][64], pre-scaled by 1/8
  bf16* kb    = (bf16*)p; p += 12582912;  // [b][h][n][64]
  bf16* vtb   = (bf16*)p; p += 12582912;  // [b][h][d][1024]
  bf16* obuf  = xb;

  cvt_bf16_kernel<<<3072, 256, 0, stream>>>(x, xb, 786432);
  cvt_bf16_kernel<<<864, 256, 0, stream>>>(qkvw, wqkvb, 221184);
  cvt_bf16_kernel<<<288, 256, 0, stream>>>(projw, wpb, 73728);
  gemm_bt_kernel<0><<<dim3(18, 64), 256, 0, stream>>>(
      xb, wqkvb, 768, 2304, qb, kb, vtb, nullptr, nullptr);
  mask_kernel<<<2048, 256, 0, stream>>>(qb, kb, mout);
  attn_kernel<<<1536, 256, 0, stream>>>(qb, kb, vtb, mout, obuf, cd);
  gemm_bt_kernel<1><<<dim3(6, 64), 256, 0, stream>>>(
      obuf, wpb, 768, 768, nullptr, nullptr, nullptr, out, projb);
}

// Round 2
// 239.843 us; speedup vs baseline: 1.1685x; 1.1685x over previous
//
#include <hip/hip_runtime.h>
#include <stdint.h>

typedef __bf16 bf16;
typedef __bf16 bf16x8 __attribute__((ext_vector_type(8)));
typedef float f32x4 __attribute__((ext_vector_type(4)));
typedef float f32x16 __attribute__((ext_vector_type(16)));
typedef uint32_t u32x4 __attribute__((ext_vector_type(4)));

#define DEVI static __device__ __forceinline__

// async global->LDS, 16B per lane. LDS dest = wave-uniform base + lane*16.
DEVI void async_ld16(void* lds, const void* g) {
  __builtin_amdgcn_global_load_lds(
      (const __attribute__((address_space(1))) void*)(uintptr_t)g,
      (__attribute__((address_space(3))) void*)(uint32_t)(uintptr_t)lds,
      16, 0, 0);
}

DEVI f32x4 vsplat(float v) { f32x4 r; r.x = v; r.y = v; r.z = v; r.w = v; return r; }

// ---------------- fused fp32 -> bf16 convert (3 arrays, 8 elems/thread) ----------
__global__ __launch_bounds__(256) void cvt3_kernel(
    const float* __restrict__ x, bf16* __restrict__ xb,
    const float* __restrict__ w1, bf16* __restrict__ w1b,
    const float* __restrict__ w2, bf16* __restrict__ w2b) {
  int i = blockIdx.x * 256 + threadIdx.x;
  const float* src; bf16* dst; int idx;
  if (i < 786432) { src = x; dst = xb; idx = i; }
  else if (i < 786432 + 221184) { src = w1; dst = w1b; idx = i - 786432; }
  else if (i < 786432 + 221184 + 73728) { src = w2; dst = w2b; idx = i - 1007616; }
  else return;
  const float4* p = (const float4*)src + (size_t)idx * 2;
  float4 a = p[0], b = p[1];
  bf16x8 o;
  o[0] = (bf16)a.x; o[1] = (bf16)a.y; o[2] = (bf16)a.z; o[3] = (bf16)a.w;
  o[4] = (bf16)b.x; o[5] = (bf16)b.y; o[6] = (bf16)b.z; o[7] = (bf16)b.w;
  *((bf16x8*)dst + idx) = o;
}

// ---------------- GEMM: C[m][n] = sum_k A[m][k]*B[n][k]  (both row-major, ld=K) ---
// 128x128 tile, BK=32, 256 thr = 4 waves (2x2), each wave 64x64 via 4x4 16x16x32 mfma.
// MODE 0: qkv epilogue -> Q(*0.125)/K as [b][h][n][64], V transposed as [b][h][d][1024]
// MODE 1: proj epilogue -> fp32 out[m*N+n] + bias[n]
template <int MODE>
__global__ __launch_bounds__(256) void gemm_bt_kernel(
    const bf16* __restrict__ A, const bf16* __restrict__ B, int K, int N,
    bf16* __restrict__ q_out, bf16* __restrict__ k_out, bf16* __restrict__ vt_out,
    float* __restrict__ f_out, const float* __restrict__ bias) {
  __shared__ bf16 As[128 * 32];
  __shared__ bf16 Bs[128 * 32];
  const int t = threadIdx.x;
  const int lane = t & 63, g = lane >> 4, ql = lane & 15;
  const int w = t >> 6, wr = w >> 1, wc = w & 1;
  const int wbase = __builtin_amdgcn_readfirstlane(t & 192);
  const int m0 = blockIdx.y * 128, n0 = blockIdx.x * 128;

  f32x4 acc[4][4];
#pragma unroll
  for (int i = 0; i < 4; i++)
#pragma unroll
    for (int j = 0; j < 4; j++) acc[i][j] = vsplat(0.f);

  for (int kt = 0; kt < K; kt += 32) {
    __syncthreads();
#pragma unroll
    for (int i = 0; i < 2; i++) {
      int unit = i * 256 + t;
      int row = unit >> 2;
      int su = (unit & 3) ^ ((row >> 1) & 3);
      async_ld16(As + (size_t)(i * 256 + wbase) * 8,
                 A + (size_t)(m0 + row) * K + kt + su * 8);
      async_ld16(Bs + (size_t)(i * 256 + wbase) * 8,
                 B + (size_t)(n0 + row) * K + kt + su * 8);
    }
    __syncthreads();
    bf16x8 af[4], bfr[4];
#pragma unroll
    for (int f = 0; f < 4; f++) {
      int ra = wr * 64 + f * 16 + ql;
      af[f] = *(const bf16x8*)(As + ra * 32 + ((g ^ ((ra >> 1) & 3)) * 8));
      int rb = wc * 64 + f * 16 + ql;
      bfr[f] = *(const bf16x8*)(Bs + rb * 32 + ((g ^ ((rb >> 1) & 3)) * 8));
    }
#pragma unroll
    for (int fm = 0; fm < 4; fm++)
#pragma unroll
      for (int fn = 0; fn < 4; fn++)
        acc[fm][fn] = __builtin_amdgcn_mfma_f32_16x16x32_bf16(af[fm], bfr[fn],
                                                              acc[fm][fn], 0, 0, 0);
  }

  if (MODE == 0) {
#pragma unroll
    for (int fm = 0; fm < 4; fm++) {
#pragma unroll
      for (int fn = 0; fn < 4; fn++) {
        int n = n0 + wc * 64 + fn * 16 + ql;
#pragma unroll
        for (int r = 0; r < 4; r++) {
          int m = m0 + wr * 64 + fm * 16 + g * 4 + r;
          int b = m >> 10, nn = m & 1023;
          float v = acc[fm][fn][r];
          if (n < 768) {  // Q, pre-scaled by 1/sqrt(64)
            int h = n >> 6, d = n & 63;
            q_out[((size_t)((b * 12 + h) * 1024 + nn)) * 64 + d] = (bf16)(v * 0.125f);
          } else if (n < 1536) {  // K
            int c = n - 768, h = c >> 6, d = c & 63;
            k_out[((size_t)((b * 12 + h) * 1024 + nn)) * 64 + d] = (bf16)v;
          } else {  // V transposed: [b][h][d][n]
            int c = n - 1536, h = c >> 6, d = c & 63;
            vt_out[((size_t)((b * 12 + h) * 64 + d)) * 1024 + nn] = (bf16)v;
          }
        }
      }
    }
  } else {
#pragma unroll
    for (int fm = 0; fm < 4; fm++) {
#pragma unroll
      for (int fn = 0; fn < 4; fn++) {
        int n = n0 + wc * 64 + fn * 16 + ql;
        float bv = bias[n];
#pragma unroll
        for (int r = 0; r < 4; r++) {
          int m = m0 + wr * 64 + fm * 16 + g * 4 + r;
          f_out[(size_t)m * N + n] = acc[fm][fn][r] + bv;
        }
      }
    }
  }
}

// ---------------- gate mask: mask[b,k] = sigmoid(dot768(q_last, k_row)/12) --------
__global__ __launch_bounds__(256) void mask_kernel(
    const bf16* __restrict__ qb, const bf16* __restrict__ kb, float* __restrict__ mout) {
  int t = threadIdx.x, lane = t & 63;
  int wid = blockIdx.x * 4 + (t >> 6);
  int b = wid >> 10, kcol = wid & 1023;
  float acc = 0.f;
#pragma unroll
  for (int h = 0; h < 12; h++) {
    const bf16* qr = qb + ((size_t)((b * 12 + h) * 1024 + 1023)) * 64;
    const bf16* kr = kb + ((size_t)((b * 12 + h) * 1024 + kcol)) * 64;
    acc += (float)qr[lane] * (float)kr[lane];
  }
#pragma unroll
  for (int off = 32; off >= 1; off >>= 1) acc += __shfl_xor(acc, off);
  if (lane == 0) {
    float x = acc * (1.f / 12.f);
    mout[(b << 10) + kcol] = 1.f / (1.f + __expf(-x));
  }
}

// ---------------- V^T *= mask (in place; gate moved out of attn loop) -------------
__global__ __launch_bounds__(256) void vscale_kernel(
    bf16* __restrict__ vt, const float* __restrict__ maskp, const int* __restrict__ cdp) {
  const bool am = (cdp[0] >= 9);
  int i = blockIdx.x * 256 + threadIdx.x;   // 98304 groups per batch
  int row = i >> 7, gcol = i & 127;
  size_t off = ((size_t)blockIdx.y * 768 + row) * 1024 + gcol * 8;
  const float* mp = maskp + blockIdx.y * 1024 + gcol * 8;
  float4 m0 = *(const float4*)mp;
  float4 m1 = *(const float4*)(mp + 4);
  float mm[8] = {m0.x, m0.y, m0.z, m0.w, m1.x, m1.y, m1.z, m1.w};
  bf16x8 v = *(bf16x8*)(vt + off);
#pragma unroll
  for (int e = 0; e < 8; e++) {
    float f = am ? mm[e] : 1.0f;
    v[e] = (bf16)((float)v[e] * f);
  }
  *(bf16x8*)(vt + off) = v;
}

// ---------------- flash attention, swapped-QK^T 32x32, in-register softmax --------
// 4 waves x 32 q-rows = 128 q / block; grid 768 (XCD-swizzled: all 8 q-tiles of a
// (b,h) on one XCD). KV tile 64. V pre-masked; denominator unmasked.
__global__ __launch_bounds__(256) void attn_kernel(
    const bf16* __restrict__ qb, const bf16* __restrict__ kb,
    const bf16* __restrict__ vt, bf16* __restrict__ ob) {
  __shared__ bf16 Ks[64 * 64];   // [kk][d], 16B slots XOR-swizzled by kk&7
  __shared__ bf16 Vs[64 * 64];   // [d][kk], swizzled by d&7
  const int t = threadIdx.x;
  const int lane = t & 63, j = lane & 31, hi = lane >> 5;
  const int w = t >> 6;
  const int wbase = __builtin_amdgcn_readfirstlane(t & 192);
  // XCD swizzle: dispatch i -> XCD i%8; give XCD x the 8 q-tiles of bh x*12..x*12+11
  int bid = (blockIdx.x & 7) * 96 + (blockIdx.x >> 3);
  const int bh = bid >> 3, qt = bid & 7;
  const int b = bh / 12, h = bh - b * 12;
  const bf16* Qp = qb + (size_t)bh * 65536;
  const bf16* Kp = kb + (size_t)bh * 65536;
  const bf16* Vp = vt + (size_t)bh * 65536;
  const int q0 = qt * 128 + w * 32;

  // Q fragments (B operand): lane (hi,j) holds Q[q0+j][hi*8 + ds*16 .. +8]
  bf16x8 qf[4];
#pragma unroll
  for (int ds = 0; ds < 4; ds++)
    qf[ds] = *(const bf16x8*)(Qp + (size_t)(q0 + j) * 64 + hi * 8 + ds * 16);

  f32x16 o0, o1;
#pragma unroll
  for (int i = 0; i < 16; i++) { o0[i] = 0.f; o1[i] = 0.f; }
  float m = -1e30f, D = 0.f;

  for (int kv0 = 0; kv0 < 1024; kv0 += 64) {
    __syncthreads();
#pragma unroll
    for (int i = 0; i < 2; i++) {
      int unit = i * 256 + t;
      int row = unit >> 3;
      int su = (unit & 7) ^ (row & 7);
      async_ld16(Ks + (size_t)(i * 256 + wbase) * 8,
                 Kp + (size_t)(kv0 + row) * 64 + su * 8);
      async_ld16(Vs + (size_t)(i * 256 + wbase) * 8,
                 Vp + (size_t)row * 1024 + kv0 + su * 8);
    }
    __syncthreads();

    // S^T[kk][q] = K Q^T : lane (hi,j) -> q=j, kk = (reg&3)+8*(reg>>2)+4*hi (+32 in s1)
    f32x16 s0, s1;
#pragma unroll
    for (int i = 0; i < 16; i++) { s0[i] = 0.f; s1[i] = 0.f; }
#pragma unroll
    for (int ds = 0; ds < 4; ds++) {
      int c = hi + 2 * ds;
      bf16x8 k0 = *(const bf16x8*)(Ks + j * 64 + ((c ^ (j & 7)) * 8));
      s0 = __builtin_amdgcn_mfma_f32_32x32x16_bf16(k0, qf[ds], s0, 0, 0, 0);
      int r1 = 32 + j;
      bf16x8 k1 = *(const bf16x8*)(Ks + r1 * 64 + ((c ^ (r1 & 7)) * 8));
      s1 = __builtin_amdgcn_mfma_f32_32x32x16_bf16(k1, qf[ds], s1, 0, 0, 0);
    }

    // online softmax: all 32 in-lane values share q=j; partner lane (^32) has other 32 kk
    float tm = s0[0];
#pragma unroll
    for (int i = 1; i < 16; i++) tm = fmaxf(tm, s0[i]);
#pragma unroll
    for (int i = 0; i < 16; i++) tm = fmaxf(tm, s1[i]);
    tm = fmaxf(tm, __shfl_xor(tm, 32));
    if (!__all(tm <= m + 8.f)) {   // T13 defer-max
      float mn = fmaxf(m, tm);
      float sc = __expf(m - mn);
      m = mn;
      D *= sc;
#pragma unroll
      for (int i = 0; i < 16; i++) { o0[i] *= sc; o1[i] *= sc; }
    }
#pragma unroll
    for (int i = 0; i < 16; i++) s0[i] = __expf(s0[i] - m);
#pragma unroll
    for (int i = 0; i < 16; i++) s1[i] = __expf(s1[i] - m);
    float rs = 0.f;
#pragma unroll
    for (int i = 0; i < 16; i++) rs += s0[i] + s1[i];
    rs += __shfl_xor(rs, 32);
    D += rs;

    // T12: P -> bf16 A-fragments via cvt_pk + permlane32_swap (no LDS round trip)
    bf16x8 pf[4];
#pragma unroll
    for (int ks = 0; ks < 4; ks++) {
      int base = 8 * (ks & 1);
      float pA0, pA1, pB0, pB1, pA2, pA3, pB2, pB3;
      if (ks & 2) {
        pA0 = s1[base]; pA1 = s1[base + 1]; pB0 = s1[base + 4]; pB1 = s1[base + 5];
        pA2 = s1[base + 2]; pA3 = s1[base + 3]; pB2 = s1[base + 6]; pB3 = s1[base + 7];
      } else {
        pA0 = s0[base]; pA1 = s0[base + 1]; pB0 = s0[base + 4]; pB1 = s0[base + 5];
        pA2 = s0[base + 2]; pA3 = s0[base + 3]; pB2 = s0[base + 6]; pB3 = s0[base + 7];
      }
      uint32_t CA, CB, CA2, CB2;
      asm("v_cvt_pk_bf16_f32 %0, %1, %2" : "=v"(CA) : "v"(pA0), "v"(pA1));
      asm("v_cvt_pk_bf16_f32 %0, %1, %2" : "=v"(CB) : "v"(pB0), "v"(pB1));
      asm("v_permlane32_swap_b32 %0, %1" : "+v"(CA), "+v"(CB));
      asm("v_cvt_pk_bf16_f32 %0, %1, %2" : "=v"(CA2) : "v"(pA2), "v"(pA3));
      asm("v_cvt_pk_bf16_f32 %0, %1, %2" : "=v"(CB2) : "v"(pB2), "v"(pB3));
      asm("v_permlane32_swap_b32 %0, %1" : "+v"(CA2), "+v"(CB2));
      u32x4 dw;
      dw[0] = CA; dw[1] = CA2; dw[2] = CB; dw[3] = CB2;
      pf[ks] = __builtin_bit_cast(bf16x8, dw);
    }

    // O[q][d] += P V' : A = P[q][kk] frags, B = V'[kk][d] (read V'^T rows from Vs)
#pragma unroll
    for (int ks = 0; ks < 4; ks++) {
      int c = hi + 2 * ks;
      bf16x8 v0 = *(const bf16x8*)(Vs + j * 64 + ((c ^ (j & 7)) * 8));
      o0 = __builtin_amdgcn_mfma_f32_32x32x16_bf16(pf[ks], v0, o0, 0, 0, 0);
      int r1 = 32 + j;
      bf16x8 v1 = *(const bf16x8*)(Vs + r1 * 64 + ((c ^ (r1 & 7)) * 8));
      o1 = __builtin_amdgcn_mfma_f32_32x32x16_bf16(pf[ks], v1, o1, 0, 0, 0);
    }
  }

  // epilogue: O[q=crow][d = j (+32)] / D[q] -> ob[b*1024+q][h*64+d]
  float dinv = 1.f / D;
#pragma unroll
  for (int reg = 0; reg < 16; reg++) {
    int qrow = (reg & 3) + 8 * (reg >> 2) + 4 * hi;
    float dv = __shfl(dinv, qrow);
    bf16* dst = ob + (size_t)(b * 1024 + q0 + qrow) * 768 + h * 64 + j;
    dst[0]  = (bf16)(o0[reg] * dv);
    dst[32] = (bf16)(o1[reg] * dv);
  }
}

// ---------------- launch ---------------------------------------------------------
extern "C" void kernel_launch(void* const* d_in, const int* in_sizes, int n_in,
                              void* d_out, int out_size, void* d_ws, size_t ws_size,
                              hipStream_t stream) {
  const float* x     = (const float*)d_in[0];
  const float* qkvw  = (const float*)d_in[1];
  const float* projw = (const float*)d_in[2];
  const float* projb = (const float*)d_in[3];
  const int*   cd    = (const int*)d_in[4];
  float* out  = (float*)d_out;
  float* mout = out + 6291456;   // mask (8,1024) fp32, second output

  char* p = (char*)d_ws;
  bf16* xb    = (bf16*)p; p += 12582912;
  bf16* wqkvb = (bf16*)p; p += 3538944;
  bf16* wpb   = (bf16*)p; p += 1179648;
  bf16* qb    = (bf16*)p; p += 12582912;  // [b][h][n][64], pre-scaled by 1/8
  bf16* kb    = (bf16*)p; p += 12582912;  // [b][h][n][64]
  bf16* vtb   = (bf16*)p; p += 12582912;  // [b][h][d][1024], gets mask-scaled
  bf16* obuf  = xb;

  cvt3_kernel<<<4224, 256, 0, stream>>>(x, xb, qkvw, wqkvb, projw, wpb);
  gemm_bt_kernel<0><<<dim3(18, 64), 256, 0, stream>>>(
      xb, wqkvb, 768, 2304, qb, kb, vtb, nullptr, nullptr);
  mask_kernel<<<2048, 256, 0, stream>>>(qb, kb, mout);
  vscale_kernel<<<dim3(384, 8), 256, 0, stream>>>(vtb, mout, cd);
  attn_kernel<<<768, 256, 0, stream>>>(qb, kb, vtb, obuf);
  gemm_bt_kernel<1><<<dim3(6, 64), 256, 0, stream>>>(
      obuf, wpb, 768, 768, nullptr, nullptr, nullptr, out, projb);
}

// Round 6
// 215.977 us; speedup vs baseline: 1.2976x; 1.1105x over previous
//
#include <hip/hip_runtime.h>
#include <stdint.h>

typedef __bf16 bf16;
typedef __bf16 bf16x8 __attribute__((ext_vector_type(8)));
typedef float f32x4 __attribute__((ext_vector_type(4)));
typedef float f32x16 __attribute__((ext_vector_type(16)));
typedef uint32_t u32x4 __attribute__((ext_vector_type(4)));

#define DEVI static __device__ __forceinline__

// async global->LDS, 16B per lane. LDS dest = wave-uniform base + lane*16 (implicit).
DEVI void async_ld16(void* lds, const void* g) {
  __builtin_amdgcn_global_load_lds(
      (const __attribute__((address_space(1))) void*)(uintptr_t)g,
      (__attribute__((address_space(3))) void*)(uint32_t)(uintptr_t)lds,
      16, 0, 0);
}

DEVI f32x4 vsplat(float v) { f32x4 r; r.x = v; r.y = v; r.z = v; r.w = v; return r; }

// ---------------- fused fp32 -> bf16 convert (3 arrays, 8 elems/thread) ----------
__global__ __launch_bounds__(256) void cvt3_kernel(
    const float* __restrict__ x, bf16* __restrict__ xb,
    const float* __restrict__ w1, bf16* __restrict__ w1b,
    const float* __restrict__ w2, bf16* __restrict__ w2b) {
  int i = blockIdx.x * 256 + threadIdx.x;
  const float* src; bf16* dst; int idx;
  if (i < 786432) { src = x; dst = xb; idx = i; }
  else if (i < 786432 + 221184) { src = w1; dst = w1b; idx = i - 786432; }
  else if (i < 786432 + 221184 + 73728) { src = w2; dst = w2b; idx = i - 1007616; }
  else return;
  const float4* p = (const float4*)src + (size_t)idx * 2;
  float4 a = p[0], b = p[1];
  bf16x8 o;
  o[0] = (bf16)a.x; o[1] = (bf16)a.y; o[2] = (bf16)a.z; o[3] = (bf16)a.w;
  o[4] = (bf16)b.x; o[5] = (bf16)b.y; o[6] = (bf16)b.z; o[7] = (bf16)b.w;
  *((bf16x8*)dst + idx) = o;
}

// ---------------- GEMM: C[m][n] = sum_k A[m][k]*B[n][k]  (both row-major, ld=K) ---
// 128x128 tile, BK=32, 4 waves (2x2), 2-phase prefetch dbuf, XCD-chunked swizzle.
// MODE 0: qkv epilogue -> Q(*0.125)/K as [b][h][n][64], V^T as [b][h][d][1024]
// MODE 1: proj epilogue -> fp32 out[m*N+n] + bias[n]
DEVI void gemm_stage(bf16* AsD, bf16* BsD, const bf16* A, const bf16* B,
                     int K, int m0, int n0, int kt, int t, int wbase) {
#pragma unroll
  for (int i = 0; i < 2; i++) {
    int unit = i * 256 + t;
    int row = unit >> 2;
    int su = (unit & 3) ^ ((row >> 1) & 3);   // inverse-swizzled global source
    async_ld16(AsD + (size_t)(i * 256 + wbase) * 8,
               A + (size_t)(m0 + row) * K + kt + su * 8);
    async_ld16(BsD + (size_t)(i * 256 + wbase) * 8,
               B + (size_t)(n0 + row) * K + kt + su * 8);
  }
}

template <int MODE>
__global__ __launch_bounds__(256) void gemm_bt_kernel(
    const bf16* __restrict__ A, const bf16* __restrict__ B, int K, int N,
    int nx, bf16* __restrict__ q_out, bf16* __restrict__ k_out,
    bf16* __restrict__ vt_out, float* __restrict__ f_out,
    const float* __restrict__ bias) {
  __shared__ bf16 As[2][128 * 32];
  __shared__ bf16 Bs[2][128 * 32];
  const int t = threadIdx.x;
  const int lane = t & 63, g = lane >> 4, ql = lane & 15;
  const int w = t >> 6, wr = w >> 1, wc = w & 1;
  const int wbase = __builtin_amdgcn_readfirstlane(t & 192);
  // XCD-chunked: xcd gets 8 contiguous m-tiles x all n-tiles (A-chunk+B -> its L2)
  const int bid = blockIdx.x;
  const int xcd = bid & 7, i6 = bid >> 3;
  const int yq = i6 / nx;
  const int m0 = (xcd * 8 + yq) * 128, n0 = (i6 - yq * nx) * 128;

  f32x4 acc[4][4];
#pragma unroll
  for (int i = 0; i < 4; i++)
#pragma unroll
    for (int j = 0; j < 4; j++) acc[i][j] = vsplat(0.f);

  gemm_stage(As[0], Bs[0], A, B, K, m0, n0, 0, t, wbase);
  int cur = 0;
  for (int kt = 0; kt < K; kt += 32) {
    __syncthreads();   // drains prefetch issued one full phase ago
    if (kt + 32 < K)
      gemm_stage(As[cur ^ 1], Bs[cur ^ 1], A, B, K, m0, n0, kt + 32, t, wbase);
    const bf16* Asc = As[cur];
    const bf16* Bsc = Bs[cur];
    bf16x8 af[4], bfr[4];
#pragma unroll
    for (int f = 0; f < 4; f++) {
      int ra = wr * 64 + f * 16 + ql;
      af[f] = *(const bf16x8*)(Asc + ra * 32 + ((g ^ ((ra >> 1) & 3)) * 8));
      int rb = wc * 64 + f * 16 + ql;
      bfr[f] = *(const bf16x8*)(Bsc + rb * 32 + ((g ^ ((rb >> 1) & 3)) * 8));
    }
    __builtin_amdgcn_s_setprio(1);
#pragma unroll
    for (int fm = 0; fm < 4; fm++)
#pragma unroll
      for (int fn = 0; fn < 4; fn++)
        acc[fm][fn] = __builtin_amdgcn_mfma_f32_16x16x32_bf16(af[fm], bfr[fn],
                                                              acc[fm][fn], 0, 0, 0);
    __builtin_amdgcn_s_setprio(0);
    cur ^= 1;
  }

  if (MODE == 0) {
#pragma unroll
    for (int fm = 0; fm < 4; fm++) {
#pragma unroll
      for (int fn = 0; fn < 4; fn++) {
        int n = n0 + wc * 64 + fn * 16 + ql;
#pragma unroll
        for (int r = 0; r < 4; r++) {
          int m = m0 + wr * 64 + fm * 16 + g * 4 + r;
          int b = m >> 10, nn = m & 1023;
          float v = acc[fm][fn][r];
          if (n < 768) {  // Q, pre-scaled by 1/sqrt(64)
            int h = n >> 6, d = n & 63;
            q_out[((size_t)((b * 12 + h) * 1024 + nn)) * 64 + d] = (bf16)(v * 0.125f);
          } else if (n < 1536) {  // K
            int c = n - 768, h = c >> 6, d = c & 63;
            k_out[((size_t)((b * 12 + h) * 1024 + nn)) * 64 + d] = (bf16)v;
          } else {  // V transposed: [b][h][d][n]
            int c = n - 1536, h = c >> 6, d = c & 63;
            vt_out[((size_t)((b * 12 + h) * 64 + d)) * 1024 + nn] = (bf16)v;
          }
        }
      }
    }
  } else {
#pragma unroll
    for (int fm = 0; fm < 4; fm++) {
#pragma unroll
      for (int fn = 0; fn < 4; fn++) {
        int n = n0 + wc * 64 + fn * 16 + ql;
        float bv = bias[n];
#pragma unroll
        for (int r = 0; r < 4; r++) {
          int m = m0 + wr * 64 + fm * 16 + g * 4 + r;
          f_out[(size_t)m * N + n] = acc[fm][fn][r] + bv;
        }
      }
    }
  }
}

// ---------------- gate mask: mask[b,k] = sigmoid(dot768(q_last, k_row)/12) --------
__global__ __launch_bounds__(256) void mask_kernel(
    const bf16* __restrict__ qb, const bf16* __restrict__ kb, float* __restrict__ mout) {
  int t = threadIdx.x, lane = t & 63;
  int wid = blockIdx.x * 4 + (t >> 6);
  int b = wid >> 10, kcol = wid & 1023;
  float acc = 0.f;
#pragma unroll
  for (int h = 0; h < 12; h++) {
    const bf16* qr = qb + ((size_t)((b * 12 + h) * 1024 + 1023)) * 64;
    const bf16* kr = kb + ((size_t)((b * 12 + h) * 1024 + kcol)) * 64;
    acc += (float)qr[lane] * (float)kr[lane];
  }
#pragma unroll
  for (int off = 32; off >= 1; off >>= 1) acc += __shfl_xor(acc, off);
  if (lane == 0) {
    float x = acc * (1.f / 12.f);
    mout[(b << 10) + kcol] = 1.f / (1.f + __expf(-x));
  }
}

// ---------------- V^T *= mask (in place; gate moved out of attn loop) -------------
__global__ __launch_bounds__(256) void vscale_kernel(
    bf16* __restrict__ vt, const float* __restrict__ maskp, const int* __restrict__ cdp) {
  const bool am = (cdp[0] >= 9);
  int i = blockIdx.x * 256 + threadIdx.x;
  int row = i >> 7, gcol = i & 127;
  size_t off = ((size_t)blockIdx.y * 768 + row) * 1024 + gcol * 8;
  const float* mp = maskp + blockIdx.y * 1024 + gcol * 8;
  float4 m0 = *(const float4*)mp;
  float4 m1 = *(const float4*)(mp + 4);
  float mm[8] = {m0.x, m0.y, m0.z, m0.w, m1.x, m1.y, m1.z, m1.w};
  bf16x8 v = *(bf16x8*)(vt + off);
#pragma unroll
  for (int e = 0; e < 8; e++) {
    float f = am ? mm[e] : 1.0f;
    v[e] = (bf16)((float)v[e] * f);
  }
  *(bf16x8*)(vt + off) = v;
}

// ---------------- flash attention, swapped-QK^T 32x32, in-register softmax --------
// 4 waves x 32 q-rows = 128 q / block; grid 768 (XCD-swizzled). KV tile 64,
// 2-phase prefetch dbuf. V pre-masked; denominator unmasked.
DEVI void attn_stage(bf16* KsD, bf16* VsD, const bf16* Kp, const bf16* Vp,
                     int kv0, int t, int wbase) {
#pragma unroll
  for (int i = 0; i < 2; i++) {
    int unit = i * 256 + t;
    int row = unit >> 3;
    int su = (unit & 7) ^ (row & 7);
    async_ld16(KsD + (size_t)(i * 256 + wbase) * 8,
               Kp + (size_t)(kv0 + row) * 64 + su * 8);
    async_ld16(VsD + (size_t)(i * 256 + wbase) * 8,
               Vp + (size_t)row * 1024 + kv0 + su * 8);
  }
}

__global__ __launch_bounds__(256) void attn_kernel(
    const bf16* __restrict__ qb, const bf16* __restrict__ kb,
    const bf16* __restrict__ vt, bf16* __restrict__ ob) {
  __shared__ bf16 Ks[2][64 * 64];   // [kk][d], 16B slots XOR-swizzled by kk&7
  __shared__ bf16 Vs[2][64 * 64];   // [d][kk], swizzled by d&7
  const int t = threadIdx.x;
  const int lane = t & 63, j = lane & 31, hi = lane >> 5;
  const int w = t >> 6;
  const int wbase = __builtin_amdgcn_readfirstlane(t & 192);
  int bid = (blockIdx.x & 7) * 96 + (blockIdx.x >> 3);
  const int bh = bid >> 3, qt = bid & 7;
  const int b = bh / 12, h = bh - b * 12;
  const bf16* Qp = qb + (size_t)bh * 65536;
  const bf16* Kp = kb + (size_t)bh * 65536;
  const bf16* Vp = vt + (size_t)bh * 65536;
  const int q0 = qt * 128 + w * 32;

  bf16x8 qf[4];
#pragma unroll
  for (int ds = 0; ds < 4; ds++)
    qf[ds] = *(const bf16x8*)(Qp + (size_t)(q0 + j) * 64 + hi * 8 + ds * 16);

  f32x16 o0, o1;
#pragma unroll
  for (int i = 0; i < 16; i++) { o0[i] = 0.f; o1[i] = 0.f; }
  float m = -1e30f, D = 0.f;

  attn_stage(Ks[0], Vs[0], Kp, Vp, 0, t, wbase);
  int cur = 0;
  for (int kv0 = 0; kv0 < 1024; kv0 += 64) {
    __syncthreads();
    if (kv0 + 64 < 1024)
      attn_stage(Ks[cur ^ 1], Vs[cur ^ 1], Kp, Vp, kv0 + 64, t, wbase);
    const bf16* Ksc = Ks[cur];
    const bf16* Vsc = Vs[cur];

    // S^T = K Q^T : lane (hi,j) -> q=j, kk = (reg&3)+8*(reg>>2)+4*hi (+32 in s1)
    f32x16 s0, s1;
#pragma unroll
    for (int i = 0; i < 16; i++) { s0[i] = 0.f; s1[i] = 0.f; }
    __builtin_amdgcn_s_setprio(1);
#pragma unroll
    for (int ds = 0; ds < 4; ds++) {
      int c = hi + 2 * ds;
      bf16x8 k0 = *(const bf16x8*)(Ksc + j * 64 + ((c ^ (j & 7)) * 8));
      s0 = __builtin_amdgcn_mfma_f32_32x32x16_bf16(k0, qf[ds], s0, 0, 0, 0);
      int r1 = 32 + j;
      bf16x8 k1 = *(const bf16x8*)(Ksc + r1 * 64 + ((c ^ (r1 & 7)) * 8));
      s1 = __builtin_amdgcn_mfma_f32_32x32x16_bf16(k1, qf[ds], s1, 0, 0, 0);
    }
    __builtin_amdgcn_s_setprio(0);

    // online softmax (row q=j fully in-lane + partner lane ^32)
    float tm = s0[0];
#pragma unroll
    for (int i = 1; i < 16; i++) tm = fmaxf(tm, s0[i]);
#pragma unroll
    for (int i = 0; i < 16; i++) tm = fmaxf(tm, s1[i]);
    tm = fmaxf(tm, __shfl_xor(tm, 32));
    if (!__all(tm <= m + 8.f)) {   // T13 defer-max
      float mn = fmaxf(m, tm);
      float sc = __expf(m - mn);
      m = mn;
      D *= sc;
#pragma unroll
      for (int i = 0; i < 16; i++) { o0[i] *= sc; o1[i] *= sc; }
    }
#pragma unroll
    for (int i = 0; i < 16; i++) s0[i] = __expf(s0[i] - m);
#pragma unroll
    for (int i = 0; i < 16; i++) s1[i] = __expf(s1[i] - m);
    float rs = 0.f;
#pragma unroll
    for (int i = 0; i < 16; i++) rs += s0[i] + s1[i];
    rs += __shfl_xor(rs, 32);
    D += rs;

    // T12: P -> bf16 A-fragments via cvt_pk + permlane32_swap
    bf16x8 pf[4];
#pragma unroll
    for (int ks = 0; ks < 4; ks++) {
      int base = 8 * (ks & 1);
      float pA0, pA1, pB0, pB1, pA2, pA3, pB2, pB3;
      if (ks & 2) {
        pA0 = s1[base]; pA1 = s1[base + 1]; pB0 = s1[base + 4]; pB1 = s1[base + 5];
        pA2 = s1[base + 2]; pA3 = s1[base + 3]; pB2 = s1[base + 6]; pB3 = s1[base + 7];
      } else {
        pA0 = s0[base]; pA1 = s0[base + 1]; pB0 = s0[base + 4]; pB1 = s0[base + 5];
        pA2 = s0[base + 2]; pA3 = s0[base + 3]; pB2 = s0[base + 6]; pB3 = s0[base + 7];
      }
      uint32_t CA, CB, CA2, CB2;
      asm("v_cvt_pk_bf16_f32 %0, %1, %2" : "=v"(CA) : "v"(pA0), "v"(pA1));
      asm("v_cvt_pk_bf16_f32 %0, %1, %2" : "=v"(CB) : "v"(pB0), "v"(pB1));
      asm("v_permlane32_swap_b32 %0, %1" : "+v"(CA), "+v"(CB));
      asm("v_cvt_pk_bf16_f32 %0, %1, %2" : "=v"(CA2) : "v"(pA2), "v"(pA3));
      asm("v_cvt_pk_bf16_f32 %0, %1, %2" : "=v"(CB2) : "v"(pB2), "v"(pB3));
      asm("v_permlane32_swap_b32 %0, %1" : "+v"(CA2), "+v"(CB2));
      u32x4 dw;
      dw[0] = CA; dw[1] = CA2; dw[2] = CB; dw[3] = CB2;
      pf[ks] = __builtin_bit_cast(bf16x8, dw);
    }

    // O += P V'
    __builtin_amdgcn_s_setprio(1);
#pragma unroll
    for (int ks = 0; ks < 4; ks++) {
      int c = hi + 2 * ks;
      bf16x8 v0 = *(const bf16x8*)(Vsc + j * 64 + ((c ^ (j & 7)) * 8));
      o0 = __builtin_amdgcn_mfma_f32_32x32x16_bf16(pf[ks], v0, o0, 0, 0, 0);
      int r1 = 32 + j;
      bf16x8 v1 = *(const bf16x8*)(Vsc + r1 * 64 + ((c ^ (r1 & 7)) * 8));
      o1 = __builtin_amdgcn_mfma_f32_32x32x16_bf16(pf[ks], v1, o1, 0, 0, 0);
    }
    __builtin_amdgcn_s_setprio(0);
    cur ^= 1;
  }

  float dinv = 1.f / D;
#pragma unroll
  for (int reg = 0; reg < 16; reg++) {
    int qrow = (reg & 3) + 8 * (reg >> 2) + 4 * hi;
    float dv = __shfl(dinv, qrow);
    bf16* dst = ob + (size_t)(b * 1024 + q0 + qrow) * 768 + h * 64 + j;
    dst[0]  = (bf16)(o0[reg] * dv);
    dst[32] = (bf16)(o1[reg] * dv);
  }
}

// ---------------- launch ---------------------------------------------------------
extern "C" void kernel_launch(void* const* d_in, const int* in_sizes, int n_in,
                              void* d_out, int out_size, void* d_ws, size_t ws_size,
                              hipStream_t stream) {
  const float* x     = (const float*)d_in[0];
  const float* qkvw  = (const float*)d_in[1];
  const float* projw = (const float*)d_in[2];
  const float* projb = (const float*)d_in[3];
  const int*   cd    = (const int*)d_in[4];
  float* out  = (float*)d_out;
  float* mout = out + 6291456;   // mask (8,1024) fp32, second output

  char* p = (char*)d_ws;
  bf16* xb    = (bf16*)p; p += 12582912;
  bf16* wqkvb = (bf16*)p; p += 3538944;
  bf16* wpb   = (bf16*)p; p += 1179648;
  bf16* qb    = (bf16*)p; p += 12582912;  // [b][h][n][64], pre-scaled by 1/8
  bf16* kb    = (bf16*)p; p += 12582912;  // [b][h][n][64]
  bf16* vtb   = (bf16*)p; p += 12582912;  // [b][h][d][1024], gets mask-scaled
  bf16* obuf  = xb;

  cvt3_kernel<<<4224, 256, 0, stream>>>(x, xb, qkvw, wqkvb, projw, wpb);
  gemm_bt_kernel<0><<<1152, 256, 0, stream>>>(
      xb, wqkvb, 768, 2304, 18, qb, kb, vtb, nullptr, nullptr);
  mask_kernel<<<2048, 256, 0, stream>>>(qb, kb, mout);
  vscale_kernel<<<dim3(384, 8), 256, 0, stream>>>(vtb, mout, cd);
  attn_kernel<<<768, 256, 0, stream>>>(qb, kb, vtb, obuf);
  gemm_bt_kernel<1><<<384, 256, 0, stream>>>(
      obuf, wpb, 768, 768, 6, nullptr, nullptr, nullptr, out, projb);
}

// Round 8
// 214.264 us; speedup vs baseline: 1.3080x; 1.0080x over previous
//
#include <hip/hip_runtime.h>
#include <stdint.h>

typedef __bf16 bf16;
typedef __bf16 bf16x8 __attribute__((ext_vector_type(8)));
typedef float f32x4 __attribute__((ext_vector_type(4)));
typedef float f32x16 __attribute__((ext_vector_type(16)));
typedef uint32_t u32x4 __attribute__((ext_vector_type(4)));

#define DEVI static __device__ __forceinline__

// async global->LDS, 16B per lane. LDS dest = wave-uniform base + lane*16 (implicit).
DEVI void async_ld16(void* lds, const void* g) {
  __builtin_amdgcn_global_load_lds(
      (const __attribute__((address_space(1))) void*)(uintptr_t)g,
      (__attribute__((address_space(3))) void*)(uint32_t)(uintptr_t)lds,
      16, 0, 0);
}

DEVI f32x4 vsplat(float v) { f32x4 r; r.x = v; r.y = v; r.z = v; r.w = v; return r; }

// ---------------- fused fp32 -> bf16 convert (3 arrays, 8 elems/thread) ----------
__global__ __launch_bounds__(256) void cvt3_kernel(
    const float* __restrict__ x, bf16* __restrict__ xb,
    const float* __restrict__ w1, bf16* __restrict__ w1b,
    const float* __restrict__ w2, bf16* __restrict__ w2b) {
  int i = blockIdx.x * 256 + threadIdx.x;
  const float* src; bf16* dst; int idx;
  if (i < 786432) { src = x; dst = xb; idx = i; }
  else if (i < 786432 + 221184) { src = w1; dst = w1b; idx = i - 786432; }
  else if (i < 786432 + 221184 + 73728) { src = w2; dst = w2b; idx = i - 1007616; }
  else return;
  const float4* p = (const float4*)src + (size_t)idx * 2;
  float4 a = p[0], b = p[1];
  bf16x8 o;
  o[0] = (bf16)a.x; o[1] = (bf16)a.y; o[2] = (bf16)a.z; o[3] = (bf16)a.w;
  o[4] = (bf16)b.x; o[5] = (bf16)b.y; o[6] = (bf16)b.z; o[7] = (bf16)b.w;
  *((bf16x8*)dst + idx) = o;
}

// ---------------- GEMM: C[m][n] = sum_k A[m][k]*B[n][k]  (both row-major, ld=K) ---
// 128x128 tile, BK=32, 4 waves (2x2). Depth-2 pipeline: 3 LDS buffers, counted
// vmcnt(4) + raw s_barrier (never drains to 0 mid-loop). XCD-chunked swizzle.
// MODE 0: qkv epilogue -> Q(*0.125)/K as [b][h][n][64], V^T as [b][h][d][1024]
// MODE 1: proj epilogue -> fp32 out[m*N+n] + bias[n]
DEVI void gemm_stage(bf16* AsD, bf16* BsD, const bf16* A, const bf16* B,
                     int K, int m0, int n0, int kt, int t, int wbase) {
#pragma unroll
  for (int i = 0; i < 2; i++) {
    int unit = i * 256 + t;
    int row = unit >> 2;
    int su = (unit & 3) ^ ((row >> 1) & 3);   // inverse-swizzled global source
    async_ld16(AsD + (size_t)(i * 256 + wbase) * 8,
               A + (size_t)(m0 + row) * K + kt + su * 8);
    async_ld16(BsD + (size_t)(i * 256 + wbase) * 8,
               B + (size_t)(n0 + row) * K + kt + su * 8);
  }
}

template <int MODE>
__global__ __launch_bounds__(256) void gemm_bt_kernel(
    const bf16* __restrict__ A, const bf16* __restrict__ B, int K, int N,
    int nx, bf16* __restrict__ q_out, bf16* __restrict__ k_out,
    bf16* __restrict__ vt_out, float* __restrict__ f_out,
    const float* __restrict__ bias) {
  __shared__ bf16 As[3][128 * 32];
  __shared__ bf16 Bs[3][128 * 32];
  const int t = threadIdx.x;
  const int lane = t & 63, g = lane >> 4, ql = lane & 15;
  const int w = t >> 6, wr = w >> 1, wc = w & 1;
  const int wbase = __builtin_amdgcn_readfirstlane(t & 192);
  // XCD-chunked: xcd gets 8 contiguous m-tiles x all n-tiles (A-chunk+B -> its L2)
  const int bid = blockIdx.x;
  const int xcd = bid & 7, i6 = bid >> 3;
  const int yq = i6 / nx;
  const int m0 = (xcd * 8 + yq) * 128, n0 = (i6 - yq * nx) * 128;
  const int nk = K >> 5;

  f32x4 acc[4][4];
#pragma unroll
  for (int i = 0; i < 4; i++)
#pragma unroll
    for (int j = 0; j < 4; j++) acc[i][j] = vsplat(0.f);

  // prologue: stage tiles 0 and 1 (8 loads/thread in flight)
  gemm_stage(As[0], Bs[0], A, B, K, m0, n0, 0, t, wbase);
  gemm_stage(As[1], Bs[1], A, B, K, m0, n0, 32, t, wbase);

  int rd = 0;  // buffer holding tile t
  for (int kt2 = 0; kt2 < nk; ++kt2) {
    // wait for tile kt2's 4 loads (leave tile kt2+1's 4 in flight), then barrier.
    if (kt2 + 1 < nk)
      asm volatile("s_waitcnt vmcnt(4)\n\ts_barrier" ::: "memory");
    else
      asm volatile("s_waitcnt vmcnt(0)\n\ts_barrier" ::: "memory");
    // issue tile kt2+2 into buffer (rd+2)%3 (safe: all waves done reading it)
    if (kt2 + 2 < nk) {
      int wb = rd >= 1 ? rd - 1 : 2;
      gemm_stage(As[wb], Bs[wb], A, B, K, m0, n0, (kt2 + 2) * 32, t, wbase);
    }
    const bf16* Asc = As[rd];
    const bf16* Bsc = Bs[rd];
    bf16x8 af[4], bfr[4];
#pragma unroll
    for (int f = 0; f < 4; f++) {
      int ra = wr * 64 + f * 16 + ql;
      af[f] = *(const bf16x8*)(Asc + ra * 32 + ((g ^ ((ra >> 1) & 3)) * 8));
      int rb = wc * 64 + f * 16 + ql;
      bfr[f] = *(const bf16x8*)(Bsc + rb * 32 + ((g ^ ((rb >> 1) & 3)) * 8));
    }
#pragma unroll
    for (int fm = 0; fm < 4; fm++)
#pragma unroll
      for (int fn = 0; fn < 4; fn++)
        acc[fm][fn] = __builtin_amdgcn_mfma_f32_16x16x32_bf16(af[fm], bfr[fn],
                                                              acc[fm][fn], 0, 0, 0);
    rd = rd < 2 ? rd + 1 : 0;
  }

  if (MODE == 0) {
#pragma unroll
    for (int fm = 0; fm < 4; fm++) {
#pragma unroll
      for (int fn = 0; fn < 4; fn++) {
        int n = n0 + wc * 64 + fn * 16 + ql;
#pragma unroll
        for (int r = 0; r < 4; r++) {
          int m = m0 + wr * 64 + fm * 16 + g * 4 + r;
          int b = m >> 10, nn = m & 1023;
          float v = acc[fm][fn][r];
          if (n < 768) {  // Q, pre-scaled by 1/sqrt(64)
            int h = n >> 6, d = n & 63;
            q_out[((size_t)((b * 12 + h) * 1024 + nn)) * 64 + d] = (bf16)(v * 0.125f);
          } else if (n < 1536) {  // K
            int c = n - 768, h = c >> 6, d = c & 63;
            k_out[((size_t)((b * 12 + h) * 1024 + nn)) * 64 + d] = (bf16)v;
          } else {  // V transposed: [b][h][d][n]
            int c = n - 1536, h = c >> 6, d = c & 63;
            vt_out[((size_t)((b * 12 + h) * 64 + d)) * 1024 + nn] = (bf16)v;
          }
        }
      }
    }
  } else {
#pragma unroll
    for (int fm = 0; fm < 4; fm++) {
#pragma unroll
      for (int fn = 0; fn < 4; fn++) {
        int n = n0 + wc * 64 + fn * 16 + ql;
        float bv = bias[n];
#pragma unroll
        for (int r = 0; r < 4; r++) {
          int m = m0 + wr * 64 + fm * 16 + g * 4 + r;
          f_out[(size_t)m * N + n] = acc[fm][fn][r] + bv;
        }
      }
    }
  }
}

// ---------------- gate mask: mask[b,k] = sigmoid(dot768(q_last, k_row)/12) --------
__global__ __launch_bounds__(256) void mask_kernel(
    const bf16* __restrict__ qb, const bf16* __restrict__ kb, float* __restrict__ mout) {
  int t = threadIdx.x, lane = t & 63;
  int wid = blockIdx.x * 4 + (t >> 6);
  int b = wid >> 10, kcol = wid & 1023;
  float acc = 0.f;
#pragma unroll
  for (int h = 0; h < 12; h++) {
    const bf16* qr = qb + ((size_t)((b * 12 + h) * 1024 + 1023)) * 64;
    const bf16* kr = kb + ((size_t)((b * 12 + h) * 1024 + kcol)) * 64;
    acc += (float)qr[lane] * (float)kr[lane];
  }
#pragma unroll
  for (int off = 32; off >= 1; off >>= 1) acc += __shfl_xor(acc, off);
  if (lane == 0) {
    float x = acc * (1.f / 12.f);
    mout[(b << 10) + kcol] = 1.f / (1.f + __expf(-x));
  }
}

// ---------------- V^T *= mask (in place; gate moved out of attn loop) -------------
__global__ __launch_bounds__(256) void vscale_kernel(
    bf16* __restrict__ vt, const float* __restrict__ maskp, const int* __restrict__ cdp) {
  const bool am = (cdp[0] >= 9);
  int i = blockIdx.x * 256 + threadIdx.x;
  int row = i >> 7, gcol = i & 127;
  size_t off = ((size_t)blockIdx.y * 768 + row) * 1024 + gcol * 8;
  const float* mp = maskp + blockIdx.y * 1024 + gcol * 8;
  float4 m0 = *(const float4*)mp;
  float4 m1 = *(const float4*)(mp + 4);
  float mm[8] = {m0.x, m0.y, m0.z, m0.w, m1.x, m1.y, m1.z, m1.w};
  bf16x8 v = *(bf16x8*)(vt + off);
#pragma unroll
  for (int e = 0; e < 8; e++) {
    float f = am ? mm[e] : 1.0f;
    v[e] = (bf16)((float)v[e] * f);
  }
  *(bf16x8*)(vt + off) = v;
}

// ---------------- flash attention, swapped-QK^T 32x32, in-register softmax --------
// 4 waves x 32 q-rows = 128 q / block; grid 768 (XCD-swizzled). KV tile 64,
// 2-phase prefetch dbuf. V pre-masked; denominator unmasked.
DEVI void attn_stage(bf16* KsD, bf16* VsD, const bf16* Kp, const bf16* Vp,
                     int kv0, int t, int wbase) {
#pragma unroll
  for (int i = 0; i < 2; i++) {
    int unit = i * 256 + t;
    int row = unit >> 3;
    int su = (unit & 7) ^ (row & 7);
    async_ld16(KsD + (size_t)(i * 256 + wbase) * 8,
               Kp + (size_t)(kv0 + row) * 64 + su * 8);
    async_ld16(VsD + (size_t)(i * 256 + wbase) * 8,
               Vp + (size_t)row * 1024 + kv0 + su * 8);
  }
}

__global__ __launch_bounds__(256) void attn_kernel(
    const bf16* __restrict__ qb, const bf16* __restrict__ kb,
    const bf16* __restrict__ vt, bf16* __restrict__ ob) {
  __shared__ bf16 Ks[2][64 * 64];   // [kk][d], 16B slots XOR-swizzled by kk&7
  __shared__ bf16 Vs[2][64 * 64];   // [d][kk], swizzled by d&7
  const int t = threadIdx.x;
  const int lane = t & 63, j = lane & 31, hi = lane >> 5;
  const int w = t >> 6;
  const int wbase = __builtin_amdgcn_readfirstlane(t & 192);
  int bid = (blockIdx.x & 7) * 96 + (blockIdx.x >> 3);
  const int bh = bid >> 3, qt = bid & 7;
  const int b = bh / 12, h = bh - b * 12;
  const bf16* Qp = qb + (size_t)bh * 65536;
  const bf16* Kp = kb + (size_t)bh * 65536;
  const bf16* Vp = vt + (size_t)bh * 65536;
  const int q0 = qt * 128 + w * 32;

  bf16x8 qf[4];
#pragma unroll
  for (int ds = 0; ds < 4; ds++)
    qf[ds] = *(const bf16x8*)(Qp + (size_t)(q0 + j) * 64 + hi * 8 + ds * 16);

  f32x16 o0, o1;
#pragma unroll
  for (int i = 0; i < 16; i++) { o0[i] = 0.f; o1[i] = 0.f; }
  float m = -1e30f, D = 0.f;

  attn_stage(Ks[0], Vs[0], Kp, Vp, 0, t, wbase);
  int cur = 0;
  for (int kv0 = 0; kv0 < 1024; kv0 += 64) {
    __syncthreads();
    if (kv0 + 64 < 1024)
      attn_stage(Ks[cur ^ 1], Vs[cur ^ 1], Kp, Vp, kv0 + 64, t, wbase);
    const bf16* Ksc = Ks[cur];
    const bf16* Vsc = Vs[cur];

    // S^T = K Q^T : lane (hi,j) -> q=j, kk = (reg&3)+8*(reg>>2)+4*hi (+32 in s1)
    f32x16 s0, s1;
#pragma unroll
    for (int i = 0; i < 16; i++) { s0[i] = 0.f; s1[i] = 0.f; }
    __builtin_amdgcn_s_setprio(1);
#pragma unroll
    for (int ds = 0; ds < 4; ds++) {
      int c = hi + 2 * ds;
      bf16x8 k0 = *(const bf16x8*)(Ksc + j * 64 + ((c ^ (j & 7)) * 8));
      s0 = __builtin_amdgcn_mfma_f32_32x32x16_bf16(k0, qf[ds], s0, 0, 0, 0);
      int r1 = 32 + j;
      bf16x8 k1 = *(const bf16x8*)(Ksc + r1 * 64 + ((c ^ (r1 & 7)) * 8));
      s1 = __builtin_amdgcn_mfma_f32_32x32x16_bf16(k1, qf[ds], s1, 0, 0, 0);
    }
    __builtin_amdgcn_s_setprio(0);

    // online softmax (row q=j fully in-lane + partner lane ^32)
    float tm = s0[0];
#pragma unroll
    for (int i = 1; i < 16; i++) tm = fmaxf(tm, s0[i]);
#pragma unroll
    for (int i = 0; i < 16; i++) tm = fmaxf(tm, s1[i]);
    tm = fmaxf(tm, __shfl_xor(tm, 32));
    if (!__all(tm <= m + 8.f)) {   // T13 defer-max
      float mn = fmaxf(m, tm);
      float sc = __expf(m - mn);
      m = mn;
      D *= sc;
#pragma unroll
      for (int i = 0; i < 16; i++) { o0[i] *= sc; o1[i] *= sc; }
    }
#pragma unroll
    for (int i = 0; i < 16; i++) s0[i] = __expf(s0[i] - m);
#pragma unroll
    for (int i = 0; i < 16; i++) s1[i] = __expf(s1[i] - m);
    float rs = 0.f;
#pragma unroll
    for (int i = 0; i < 16; i++) rs += s0[i] + s1[i];
    rs += __shfl_xor(rs, 32);
    D += rs;

    // T12: P -> bf16 A-fragments via cvt_pk + permlane32_swap
    bf16x8 pf[4];
#pragma unroll
    for (int ks = 0; ks < 4; ks++) {
      int base = 8 * (ks & 1);
      float pA0, pA1, pB0, pB1, pA2, pA3, pB2, pB3;
      if (ks & 2) {
        pA0 = s1[base]; pA1 = s1[base + 1]; pB0 = s1[base + 4]; pB1 = s1[base + 5];
        pA2 = s1[base + 2]; pA3 = s1[base + 3]; pB2 = s1[base + 6]; pB3 = s1[base + 7];
      } else {
        pA0 = s0[base]; pA1 = s0[base + 1]; pB0 = s0[base + 4]; pB1 = s0[base + 5];
        pA2 = s0[base + 2]; pA3 = s0[base + 3]; pB2 = s0[base + 6]; pB3 = s0[base + 7];
      }
      uint32_t CA, CB, CA2, CB2;
      asm("v_cvt_pk_bf16_f32 %0, %1, %2" : "=v"(CA) : "v"(pA0), "v"(pA1));
      asm("v_cvt_pk_bf16_f32 %0, %1, %2" : "=v"(CB) : "v"(pB0), "v"(pB1));
      asm("v_permlane32_swap_b32 %0, %1" : "+v"(CA), "+v"(CB));
      asm("v_cvt_pk_bf16_f32 %0, %1, %2" : "=v"(CA2) : "v"(pA2), "v"(pA3));
      asm("v_cvt_pk_bf16_f32 %0, %1, %2" : "=v"(CB2) : "v"(pB2), "v"(pB3));
      asm("v_permlane32_swap_b32 %0, %1" : "+v"(CA2), "+v"(CB2));
      u32x4 dw;
      dw[0] = CA; dw[1] = CA2; dw[2] = CB; dw[3] = CB2;
      pf[ks] = __builtin_bit_cast(bf16x8, dw);
    }

    // O += P V'
    __builtin_amdgcn_s_setprio(1);
#pragma unroll
    for (int ks = 0; ks < 4; ks++) {
      int c = hi + 2 * ks;
      bf16x8 v0 = *(const bf16x8*)(Vsc + j * 64 + ((c ^ (j & 7)) * 8));
      o0 = __builtin_amdgcn_mfma_f32_32x32x16_bf16(pf[ks], v0, o0, 0, 0, 0);
      int r1 = 32 + j;
      bf16x8 v1 = *(const bf16x8*)(Vsc + r1 * 64 + ((c ^ (r1 & 7)) * 8));
      o1 = __builtin_amdgcn_mfma_f32_32x32x16_bf16(pf[ks], v1, o1, 0, 0, 0);
    }
    __builtin_amdgcn_s_setprio(0);
    cur ^= 1;
  }

  float dinv = 1.f / D;
#pragma unroll
  for (int reg = 0; reg < 16; reg++) {
    int qrow = (reg & 3) + 8 * (reg >> 2) + 4 * hi;
    float dv = __shfl(dinv, qrow);
    bf16* dst = ob + (size_t)(b * 1024 + q0 + qrow) * 768 + h * 64 + j;
    dst[0]  = (bf16)(o0[reg] * dv);
    dst[32] = (bf16)(o1[reg] * dv);
  }
}

// ---------------- launch ---------------------------------------------------------
extern "C" void kernel_launch(void* const* d_in, const int* in_sizes, int n_in,
                              void* d_out, int out_size, void* d_ws, size_t ws_size,
                              hipStream_t stream) {
  const float* x     = (const float*)d_in[0];
  const float* qkvw  = (const float*)d_in[1];
  const float* projw = (const float*)d_in[2];
  const float* projb = (const float*)d_in[3];
  const int*   cd    = (const int*)d_in[4];
  float* out  = (float*)d_out;
  float* mout = out + 6291456;   // mask (8,1024) fp32, second output

  char* p = (char*)d_ws;
  bf16* xb    = (bf16*)p; p += 12582912;
  bf16* wqkvb = (bf16*)p; p += 3538944;
  bf16* wpb   = (bf16*)p; p += 1179648;
  bf16* qb    = (bf16*)p; p += 12582912;  // [b][h][n][64], pre-scaled by 1/8
  bf16* kb    = (bf16*)p; p += 12582912;  // [b][h][n][64]
  bf16* vtb   = (bf16*)p; p += 12582912;  // [b][h][d][1024], gets mask-scaled
  bf16* obuf  = xb;

  cvt3_kernel<<<4224, 256, 0, stream>>>(x, xb, qkvw, wqkvb, projw, wpb);
  gemm_bt_kernel<0><<<1152, 256, 0, stream>>>(
      xb, wqkvb, 768, 2304, 18, qb, kb, vtb, nullptr, nullptr);
  mask_kernel<<<2048, 256, 0, stream>>>(qb, kb, mout);
  vscale_kernel<<<dim3(384, 8), 256, 0, stream>>>(vtb, mout, cd);
  attn_kernel<<<768, 256, 0, stream>>>(qb, kb, vtb, obuf);
  gemm_bt_kernel<1><<<384, 256, 0, stream>>>(
      obuf, wpb, 768, 768, 6, nullptr, nullptr, nullptr, out, projb);
}

// Round 11
// 213.212 us; speedup vs baseline: 1.3144x; 1.0049x over previous
//
#include <hip/hip_runtime.h>
#include <stdint.h>

typedef __bf16 bf16;
typedef __bf16 bf16x8 __attribute__((ext_vector_type(8)));
typedef float f32x4 __attribute__((ext_vector_type(4)));
typedef float f32x16 __attribute__((ext_vector_type(16)));
typedef uint32_t u32x4 __attribute__((ext_vector_type(4)));

#define DEVI static __device__ __forceinline__

// async global->LDS, 16B per lane. LDS dest = wave-uniform base + lane*16 (implicit).
DEVI void async_ld16(void* lds, const void* g) {
  __builtin_amdgcn_global_load_lds(
      (const __attribute__((address_space(1))) void*)(uintptr_t)g,
      (__attribute__((address_space(3))) void*)(uint32_t)(uintptr_t)lds,
      16, 0, 0);
}

DEVI f32x4 vsplat(float v) { f32x4 r; r.x = v; r.y = v; r.z = v; r.w = v; return r; }

// ---------------- fused fp32 -> bf16 convert (3 arrays, 8 elems/thread) ----------
__global__ __launch_bounds__(256) void cvt3_kernel(
    const float* __restrict__ x, bf16* __restrict__ xb,
    const float* __restrict__ w1, bf16* __restrict__ w1b,
    const float* __restrict__ w2, bf16* __restrict__ w2b) {
  int i = blockIdx.x * 256 + threadIdx.x;
  const float* src; bf16* dst; int idx;
  if (i < 786432) { src = x; dst = xb; idx = i; }
  else if (i < 786432 + 221184) { src = w1; dst = w1b; idx = i - 786432; }
  else if (i < 786432 + 221184 + 73728) { src = w2; dst = w2b; idx = i - 1007616; }
  else return;
  const float4* p = (const float4*)src + (size_t)idx * 2;
  float4 a = p[0], b = p[1];
  bf16x8 o;
  o[0] = (bf16)a.x; o[1] = (bf16)a.y; o[2] = (bf16)a.z; o[3] = (bf16)a.w;
  o[4] = (bf16)b.x; o[5] = (bf16)b.y; o[6] = (bf16)b.z; o[7] = (bf16)b.w;
  *((bf16x8*)dst + idx) = o;
}

// ---------------- GEMM: C[m][n] = sum_k A[m][k]*B[n][k]  (both row-major, ld=K) ---
// BM=256 BN=128 BK=64, 512 thr = 8 waves (4M x 2N), each wave 64x64 out (4x4 frags).
// 3 LDS buffers, depth-2 counted vmcnt(6). Rows are 64 elems (128B = 8x16B slots),
// slot XOR-swizzled by row&7 (same geometry as attn staging, verified).
// MODE 0: qkv epilogue -> Q(*0.125)/K as [b][h][n][64], V^T as [b][h][d][1024]
// MODE 1: proj epilogue -> fp32 out[m*N+n] + bias[n]
DEVI void gemm_stage(bf16* AsD, bf16* BsD, const bf16* A, const bf16* B,
                     int K, int m0, int n0, int kt, int t, int wbase) {
  // A: 256 rows x 128B = 2048 16B-units; 512 thr -> 4 passes
#pragma unroll
  for (int p = 0; p < 4; p++) {
    int unit = p * 512 + t;
    int row = unit >> 3;
    int su = (unit & 7) ^ (row & 7);
    async_ld16(AsD + (size_t)(p * 512 + wbase) * 8,
               A + (size_t)(m0 + row) * K + kt + su * 8);
  }
  // B: 128 rows -> 1024 units; 2 passes
#pragma unroll
  for (int p = 0; p < 2; p++) {
    int unit = p * 512 + t;
    int row = unit >> 3;
    int su = (unit & 7) ^ (row & 7);
    async_ld16(BsD + (size_t)(p * 512 + wbase) * 8,
               B + (size_t)(n0 + row) * K + kt + su * 8);
  }
}

template <int MODE>
__global__ __launch_bounds__(512, 1) void gemm_bt_kernel(
    const bf16* __restrict__ A, const bf16* __restrict__ B, int K, int N,
    int nx, bf16* __restrict__ q_out, bf16* __restrict__ k_out,
    bf16* __restrict__ vt_out, float* __restrict__ f_out,
    const float* __restrict__ bias) {
  __shared__ bf16 As[3][256 * 64];   // 96 KB
  __shared__ bf16 Bs[3][128 * 64];   // 48 KB
  const int t = threadIdx.x;
  const int lane = t & 63, g = lane >> 4, ql = lane & 15;
  const int w = t >> 6, wr = w >> 1, wc = w & 1;   // 4M x 2N wave grid
  const int wbase = __builtin_amdgcn_readfirstlane(t & 448);
  // XCD-chunked: xcd gets 4 contiguous m-tiles x all n-tiles
  const int bid = blockIdx.x;
  const int xcd = bid & 7, i6 = bid >> 3;
  const int yq = i6 / nx;
  const int m0 = (xcd * 4 + yq) * 256, n0 = (i6 - yq * nx) * 128;
  const int nk = K >> 6;

  f32x4 acc[4][4];
#pragma unroll
  for (int i = 0; i < 4; i++)
#pragma unroll
    for (int j = 0; j < 4; j++) acc[i][j] = vsplat(0.f);

  // prologue: stage tiles 0 and 1 (12 loads/thread in flight)
  gemm_stage(As[0], Bs[0], A, B, K, m0, n0, 0, t, wbase);
  gemm_stage(As[1], Bs[1], A, B, K, m0, n0, 64, t, wbase);

  int rd = 0;
  for (int kt2 = 0; kt2 < nk; ++kt2) {
    // wait tile kt2's 6 loads (leave tile kt2+1's 6 in flight), then barrier
    if (kt2 + 1 < nk)
      asm volatile("s_waitcnt vmcnt(6)\n\ts_barrier" ::: "memory");
    else
      asm volatile("s_waitcnt vmcnt(0)\n\ts_barrier" ::: "memory");
    if (kt2 + 2 < nk) {
      int wb = rd >= 1 ? rd - 1 : 2;
      gemm_stage(As[wb], Bs[wb], A, B, K, m0, n0, (kt2 + 2) * 64, t, wbase);
    }
    const bf16* Asc = As[rd];
    const bf16* Bsc = Bs[rd];
    bf16x8 af[2][4], bfr[2][4];
#pragma unroll
    for (int kh = 0; kh < 2; kh++) {
#pragma unroll
      for (int f = 0; f < 4; f++) {
        int ra = wr * 64 + f * 16 + ql;
        af[kh][f] = *(const bf16x8*)(Asc + ra * 64 + (((kh * 4 + g) ^ (ra & 7)) * 8));
        int rb = wc * 64 + f * 16 + ql;
        bfr[kh][f] = *(const bf16x8*)(Bsc + rb * 64 + (((kh * 4 + g) ^ (rb & 7)) * 8));
      }
    }
#pragma unroll
    for (int kh = 0; kh < 2; kh++)
#pragma unroll
      for (int fm = 0; fm < 4; fm++)
#pragma unroll
        for (int fn = 0; fn < 4; fn++)
          acc[fm][fn] = __builtin_amdgcn_mfma_f32_16x16x32_bf16(
              af[kh][fm], bfr[kh][fn], acc[fm][fn], 0, 0, 0);
    rd = rd < 2 ? rd + 1 : 0;
  }

  if (MODE == 0) {
#pragma unroll
    for (int fm = 0; fm < 4; fm++) {
#pragma unroll
      for (int fn = 0; fn < 4; fn++) {
        int n = n0 + wc * 64 + fn * 16 + ql;
#pragma unroll
        for (int r = 0; r < 4; r++) {
          int m = m0 + wr * 64 + fm * 16 + g * 4 + r;
          int b = m >> 10, nn = m & 1023;
          float v = acc[fm][fn][r];
          if (n < 768) {  // Q, pre-scaled by 1/sqrt(64)
            int h = n >> 6, d = n & 63;
            q_out[((size_t)((b * 12 + h) * 1024 + nn)) * 64 + d] = (bf16)(v * 0.125f);
          } else if (n < 1536) {  // K
            int c = n - 768, h = c >> 6, d = c & 63;
            k_out[((size_t)((b * 12 + h) * 1024 + nn)) * 64 + d] = (bf16)v;
          } else {  // V transposed: [b][h][d][n]
            int c = n - 1536, h = c >> 6, d = c & 63;
            vt_out[((size_t)((b * 12 + h) * 64 + d)) * 1024 + nn] = (bf16)v;
          }
        }
      }
    }
  } else {
#pragma unroll
    for (int fm = 0; fm < 4; fm++) {
#pragma unroll
      for (int fn = 0; fn < 4; fn++) {
        int n = n0 + wc * 64 + fn * 16 + ql;
        float bv = bias[n];
#pragma unroll
        for (int r = 0; r < 4; r++) {
          int m = m0 + wr * 64 + fm * 16 + g * 4 + r;
          f_out[(size_t)m * N + n] = acc[fm][fn][r] + bv;
        }
      }
    }
  }
}

// ---------------- gate mask: mask[b,k] = sigmoid(dot768(q_last, k_row)/12) --------
__global__ __launch_bounds__(256) void mask_kernel(
    const bf16* __restrict__ qb, const bf16* __restrict__ kb, float* __restrict__ mout) {
  int t = threadIdx.x, lane = t & 63;
  int wid = blockIdx.x * 4 + (t >> 6);
  int b = wid >> 10, kcol = wid & 1023;
  float acc = 0.f;
#pragma unroll
  for (int h = 0; h < 12; h++) {
    const bf16* qr = qb + ((size_t)((b * 12 + h) * 1024 + 1023)) * 64;
    const bf16* kr = kb + ((size_t)((b * 12 + h) * 1024 + kcol)) * 64;
    acc += (float)qr[lane] * (float)kr[lane];
  }
#pragma unroll
  for (int off = 32; off >= 1; off >>= 1) acc += __shfl_xor(acc, off);
  if (lane == 0) {
    float x = acc * (1.f / 12.f);
    mout[(b << 10) + kcol] = 1.f / (1.f + __expf(-x));
  }
}

// ---------------- V^T *= mask (in place; gate moved out of attn loop) -------------
__global__ __launch_bounds__(256) void vscale_kernel(
    bf16* __restrict__ vt, const float* __restrict__ maskp, const int* __restrict__ cdp) {
  const bool am = (cdp[0] >= 9);
  int i = blockIdx.x * 256 + threadIdx.x;
  int row = i >> 7, gcol = i & 127;
  size_t off = ((size_t)blockIdx.y * 768 + row) * 1024 + gcol * 8;
  const float* mp = maskp + blockIdx.y * 1024 + gcol * 8;
  float4 m0 = *(const float4*)mp;
  float4 m1 = *(const float4*)(mp + 4);
  float mm[8] = {m0.x, m0.y, m0.z, m0.w, m1.x, m1.y, m1.z, m1.w};
  bf16x8 v = *(bf16x8*)(vt + off);
#pragma unroll
  for (int e = 0; e < 8; e++) {
    float f = am ? mm[e] : 1.0f;
    v[e] = (bf16)((float)v[e] * f);
  }
  *(bf16x8*)(vt + off) = v;
}

// ---------------- flash attention, swapped-QK^T 32x32, in-register softmax --------
// 4 waves x 32 q-rows = 128 q / block; grid 768 (XCD-swizzled). KV tile 64,
// 2-phase prefetch dbuf. V pre-masked; denominator unmasked.
DEVI void attn_stage(bf16* KsD, bf16* VsD, const bf16* Kp, const bf16* Vp,
                     int kv0, int t, int wbase) {
#pragma unroll
  for (int i = 0; i < 2; i++) {
    int unit = i * 256 + t;
    int row = unit >> 3;
    int su = (unit & 7) ^ (row & 7);
    async_ld16(KsD + (size_t)(i * 256 + wbase) * 8,
               Kp + (size_t)(kv0 + row) * 64 + su * 8);
    async_ld16(VsD + (size_t)(i * 256 + wbase) * 8,
               Vp + (size_t)row * 1024 + kv0 + su * 8);
  }
}

__global__ __launch_bounds__(256) void attn_kernel(
    const bf16* __restrict__ qb, const bf16* __restrict__ kb,
    const bf16* __restrict__ vt, bf16* __restrict__ ob) {
  __shared__ bf16 Ks[2][64 * 64];   // [kk][d], 16B slots XOR-swizzled by kk&7
  __shared__ bf16 Vs[2][64 * 64];   // [d][kk], swizzled by d&7
  const int t = threadIdx.x;
  const int lane = t & 63, j = lane & 31, hi = lane >> 5;
  const int w = t >> 6;
  const int wbase = __builtin_amdgcn_readfirstlane(t & 192);
  int bid = (blockIdx.x & 7) * 96 + (blockIdx.x >> 3);
  const int bh = bid >> 3, qt = bid & 7;
  const int b = bh / 12, h = bh - b * 12;
  const bf16* Qp = qb + (size_t)bh * 65536;
  const bf16* Kp = kb + (size_t)bh * 65536;
  const bf16* Vp = vt + (size_t)bh * 65536;
  const int q0 = qt * 128 + w * 32;

  bf16x8 qf[4];
#pragma unroll
  for (int ds = 0; ds < 4; ds++)
    qf[ds] = *(const bf16x8*)(Qp + (size_t)(q0 + j) * 64 + hi * 8 + ds * 16);

  f32x16 o0, o1;
#pragma unroll
  for (int i = 0; i < 16; i++) { o0[i] = 0.f; o1[i] = 0.f; }
  float m = -1e30f, D = 0.f;

  attn_stage(Ks[0], Vs[0], Kp, Vp, 0, t, wbase);
  int cur = 0;
  for (int kv0 = 0; kv0 < 1024; kv0 += 64) {
    __syncthreads();
    if (kv0 + 64 < 1024)
      attn_stage(Ks[cur ^ 1], Vs[cur ^ 1], Kp, Vp, kv0 + 64, t, wbase);
    const bf16* Ksc = Ks[cur];
    const bf16* Vsc = Vs[cur];

    // S^T = K Q^T : lane (hi,j) -> q=j, kk = (reg&3)+8*(reg>>2)+4*hi (+32 in s1)
    f32x16 s0, s1;
#pragma unroll
    for (int i = 0; i < 16; i++) { s0[i] = 0.f; s1[i] = 0.f; }
    __builtin_amdgcn_s_setprio(1);
#pragma unroll
    for (int ds = 0; ds < 4; ds++) {
      int c = hi + 2 * ds;
      bf16x8 k0 = *(const bf16x8*)(Ksc + j * 64 + ((c ^ (j & 7)) * 8));
      s0 = __builtin_amdgcn_mfma_f32_32x32x16_bf16(k0, qf[ds], s0, 0, 0, 0);
      int r1 = 32 + j;
      bf16x8 k1 = *(const bf16x8*)(Ksc + r1 * 64 + ((c ^ (r1 & 7)) * 8));
      s1 = __builtin_amdgcn_mfma_f32_32x32x16_bf16(k1, qf[ds], s1, 0, 0, 0);
    }
    __builtin_amdgcn_s_setprio(0);

    // online softmax (row q=j fully in-lane + partner lane ^32)
    float tm = s0[0];
#pragma unroll
    for (int i = 1; i < 16; i++) tm = fmaxf(tm, s0[i]);
#pragma unroll
    for (int i = 0; i < 16; i++) tm = fmaxf(tm, s1[i]);
    tm = fmaxf(tm, __shfl_xor(tm, 32));
    if (!__all(tm <= m + 8.f)) {   // T13 defer-max
      float mn = fmaxf(m, tm);
      float sc = __expf(m - mn);
      m = mn;
      D *= sc;
#pragma unroll
      for (int i = 0; i < 16; i++) { o0[i] *= sc; o1[i] *= sc; }
    }
#pragma unroll
    for (int i = 0; i < 16; i++) s0[i] = __expf(s0[i] - m);
#pragma unroll
    for (int i = 0; i < 16; i++) s1[i] = __expf(s1[i] - m);
    float rs = 0.f;
#pragma unroll
    for (int i = 0; i < 16; i++) rs += s0[i] + s1[i];
    rs += __shfl_xor(rs, 32);
    D += rs;

    // T12: P -> bf16 A-fragments via cvt_pk + permlane32_swap
    bf16x8 pf[4];
#pragma unroll
    for (int ks = 0; ks < 4; ks++) {
      int base = 8 * (ks & 1);
      float pA0, pA1, pB0, pB1, pA2, pA3, pB2, pB3;
      if (ks & 2) {
        pA0 = s1[base]; pA1 = s1[base + 1]; pB0 = s1[base + 4]; pB1 = s1[base + 5];
        pA2 = s1[base + 2]; pA3 = s1[base + 3]; pB2 = s1[base + 6]; pB3 = s1[base + 7];
      } else {
        pA0 = s0[base]; pA1 = s0[base + 1]; pB0 = s0[base + 4]; pB1 = s0[base + 5];
        pA2 = s0[base + 2]; pA3 = s0[base + 3]; pB2 = s0[base + 6]; pB3 = s0[base + 7];
      }
      uint32_t CA, CB, CA2, CB2;
      asm("v_cvt_pk_bf16_f32 %0, %1, %2" : "=v"(CA) : "v"(pA0), "v"(pA1));
      asm("v_cvt_pk_bf16_f32 %0, %1, %2" : "=v"(CB) : "v"(pB0), "v"(pB1));
      asm("v_permlane32_swap_b32 %0, %1" : "+v"(CA), "+v"(CB));
      asm("v_cvt_pk_bf16_f32 %0, %1, %2" : "=v"(CA2) : "v"(pA2), "v"(pA3));
      asm("v_cvt_pk_bf16_f32 %0, %1, %2" : "=v"(CB2) : "v"(pB2), "v"(pB3));
      asm("v_permlane32_swap_b32 %0, %1" : "+v"(CA2), "+v"(CB2));
      u32x4 dw;
      dw[0] = CA; dw[1] = CA2; dw[2] = CB; dw[3] = CB2;
      pf[ks] = __builtin_bit_cast(bf16x8, dw);
    }

    // O += P V'
    __builtin_amdgcn_s_setprio(1);
#pragma unroll
    for (int ks = 0; ks < 4; ks++) {
      int c = hi + 2 * ks;
      bf16x8 v0 = *(const bf16x8*)(Vsc + j * 64 + ((c ^ (j & 7)) * 8));
      o0 = __builtin_amdgcn_mfma_f32_32x32x16_bf16(pf[ks], v0, o0, 0, 0, 0);
      int r1 = 32 + j;
      bf16x8 v1 = *(const bf16x8*)(Vsc + r1 * 64 + ((c ^ (r1 & 7)) * 8));
      o1 = __builtin_amdgcn_mfma_f32_32x32x16_bf16(pf[ks], v1, o1, 0, 0, 0);
    }
    __builtin_amdgcn_s_setprio(0);
    cur ^= 1;
  }

  float dinv = 1.f / D;
#pragma unroll
  for (int reg = 0; reg < 16; reg++) {
    int qrow = (reg & 3) + 8 * (reg >> 2) + 4 * hi;
    float dv = __shfl(dinv, qrow);
    bf16* dst = ob + (size_t)(b * 1024 + q0 + qrow) * 768 + h * 64 + j;
    dst[0]  = (bf16)(o0[reg] * dv);
    dst[32] = (bf16)(o1[reg] * dv);
  }
}

// ---------------- launch ---------------------------------------------------------
extern "C" void kernel_launch(void* const* d_in, const int* in_sizes, int n_in,
                              void* d_out, int out_size, void* d_ws, size_t ws_size,
                              hipStream_t stream) {
  const float* x     = (const float*)d_in[0];
  const float* qkvw  = (const float*)d_in[1];
  const float* projw = (const float*)d_in[2];
  const float* projb = (const float*)d_in[3];
  const int*   cd    = (const int*)d_in[4];
  float* out  = (float*)d_out;
  float* mout = out + 6291456;   // mask (8,1024) fp32, second output

  char* p = (char*)d_ws;
  bf16* xb    = (bf16*)p; p += 12582912;
  bf16* wqkvb = (bf16*)p; p += 3538944;
  bf16* wpb   = (bf16*)p; p += 1179648;
  bf16* qb    = (bf16*)p; p += 12582912;  // [b][h][n][64], pre-scaled by 1/8
  bf16* kb    = (bf16*)p; p += 12582912;  // [b][h][n][64]
  bf16* vtb   = (bf16*)p; p += 12582912;  // [b][h][d][1024], gets mask-scaled
  bf16* obuf  = xb;

  cvt3_kernel<<<4224, 256, 0, stream>>>(x, xb, qkvw, wqkvb, projw, wpb);
  // gemm<0>: M=8192 (32 m-tiles of 256), N=2304 (18 n-tiles of 128) -> 576 blocks
  gemm_bt_kernel<0><<<576, 512, 0, stream>>>(
      xb, wqkvb, 768, 2304, 18, qb, kb, vtb, nullptr, nullptr);
  mask_kernel<<<2048, 256, 0, stream>>>(qb, kb, mout);
  vscale_kernel<<<dim3(384, 8), 256, 0, stream>>>(vtb, mout, cd);
  attn_kernel<<<768, 256, 0, stream>>>(qb, kb, vtb, obuf);
  // gemm<1>: M=8192, N=768 (6 n-tiles of 128) -> 192 blocks
  gemm_bt_kernel<1><<<192, 512, 0, stream>>>(
      obuf, wpb, 768, 768, 6, nullptr, nullptr, nullptr, out, projb);
}